// Round 4
// baseline (5092.915 us; speedup 1.0000x reference)
//
#include <hip/hip_runtime.h>

#define K_CLUSTERS 512
#define FDIM 64
#define RPB 512      // rows per block; grid = N/RPB = 256 (1 block/CU, LDS-bound)
#define RT 8         // rows per wave-tile
#define NTILES 4     // tiles per wave: RPB / (16 waves * RT)

typedef float vf4 __attribute__((ext_vector_type(4)));

// Transpose W [F=64][K=512] -> Wt [K][F] (for epilogue gather), wsq[k].
// UNCHANGED (absmax 0.0 proven).
__global__ __launch_bounds__(64) void vq_prep(const float* __restrict__ W,
                                              float* __restrict__ Wt,
                                              float* __restrict__ wsq) {
    int k = blockIdx.x;
    int f = threadIdx.x;
    float w = W[f * K_CLUSTERS + k];
    Wt[k * FDIM + f] = w;
    float s = w * w;
#pragma unroll
    for (int off = 32; off > 0; off >>= 1) s += __shfl_xor(s, off, 64);
    if (f == 0) wsq[k] = s;
}

// Fused argmin + zq + diff + one-hot.
// W in LDS (128 KB, XOR-swizzled; swizzle now also folds (c>>4)&3 so the four
// 16-lane quarters hit distinct bank groups). z broadcasts from global
// (wave-uniform addr -> one L1 transaction on the otherwise-idle VMEM pipe).
// Cluster dim = 1 per lane x 8 passes (round 3's 4-per-lane made the working
// set ~100 floats; the allocator pins 64 VGPRs at 1024-thread blocks no matter
// what, spilling ~550 MB to scratch -> WRITE_SIZE 882 MB vs 328 ideal).
// Working set now ~52 regs: acc[8]+wv+bd/bk[8]+sA[8]+zb -> fits 64, no spill.
// All arithmetic chains bit-identical to the proven kernels (absmax 0.0):
// ascending-f fmaf dot; fmaf(-2,dot,s)+wsq; 8-lane sumz chains + shfl_xor
// tree (== exact pairwise tree, proven round 3); contract-off epilogue;
// lex-min (d,k) == np.argmin first-index rule (order-agnostic lex compare).
__global__ __launch_bounds__(1024) void vq_fused(const float* __restrict__ z,
                                                 const float* __restrict__ W,
                                                 const float* __restrict__ Wt,
                                                 const float* __restrict__ wsq,
                                                 float* __restrict__ out_zq,
                                                 float* __restrict__ out_idx,
                                                 float* __restrict__ enc,
                                                 float* __restrict__ out_diff) {
    // sW4[c*16 + (f4 ^ (c&15) ^ ((c>>4)&3))] = W[4*f4..4*f4+3][c]
    __shared__ vf4 sW4[K_CLUSTERS * 16];   // 128 KB, the only LDS

    const int tid = threadIdx.x;
    const int w = tid >> 6;
    const int l = tid & 63;
    const int xh = (l & 15) ^ ((l >> 4) & 3);   // read-side swizzle constant

    // ---- Stage W into LDS (coalesced vf4 reads, swizzled scalar writes) ----
    {
        float* sWf = (float*)sW4;
        const vf4* Wg4 = (const vf4*)W;
#pragma unroll
        for (int it = 0; it < 8; it++) {
            int u4 = it * 1024 + tid;       // vf4 index over W (8192 total)
            vf4 v = Wg4[u4];
            int u = u4 << 2;                // float index; 4 elems same f, c0..c0+3
            int f = u >> 9;
            int c0 = u & 511;
            int f4 = f >> 2, m = f & 3;
#pragma unroll
            for (int e = 0; e < 4; e++) {
                int c = c0 + e;
                int chunk = f4 ^ (c & 15) ^ ((c >> 4) & 3);
                sWf[c * 64 + (chunk << 2) + m] = v[e];
            }
        }
    }
    __syncthreads();  // the only barrier in the kernel

    const int rowW = blockIdx.x * RPB + w * (RT * NTILES);
    const vf4* zg4 = (const vf4*)z;

#pragma unroll 1
    for (int t = 0; t < NTILES; t++) {
        const int row0 = rowW + t * RT;

        // ---- sumz: 8 lanes per row, one exact accumulator chain per lane ----
        // (proven bit-exact in round 3)
        float srow;
        {
            const float* zr = z + (size_t)(row0 + (l >> 3)) * FDIM;
            const int j = l & 7;
            float rj;
            {
#pragma clang fp contract(off)
                rj = zr[j] * zr[j];
#pragma unroll
                for (int b = 8; b < 64; b += 8) rj += zr[b + j] * zr[b + j];
            }
            float s01 = rj + __shfl_xor(rj, 1, 64);
            float s03 = s01 + __shfl_xor(s01, 2, 64);
            srow = s03 + __shfl_xor(s03, 4, 64);
        }
        float sA[RT];
#pragma unroll
        for (int r = 0; r < RT; r++) sA[r] = __shfl(srow, r << 3, 64);

        float bd[RT];
        int bk[RT];
#pragma unroll
        for (int r = 0; r < RT; r++) { bd[r] = INFINITY; bk[r] = 0; }

        const vf4* zt = zg4 + (size_t)row0 * 16;  // wave-uniform z tile base

        // ---- 8 passes: lane l owns cluster c = pass*64 + l ----
#pragma unroll 1
        for (int pass = 0; pass < 8; pass++) {
            const int c = (pass << 6) + l;
            const float q = wsq[c];
            const vf4* wB = sW4 + ((size_t)c << 4);
            float a0 = 0.0f, a1 = 0.0f, a2 = 0.0f, a3 = 0.0f;
            float a4 = 0.0f, a5 = 0.0f, a6 = 0.0f, a7 = 0.0f;
#pragma unroll
            for (int f4 = 0; f4 < 16; f4++) {
                const int sl = f4 ^ xh;        // swizzled chunk for this lane
                vf4 wv = wB[sl];
                {
                    vf4 zb = zt[f4];           // row 0 (uniform addr -> L1 bcast)
                    a0 = fmaf(zb.x, wv.x, a0); a0 = fmaf(zb.y, wv.y, a0);
                    a0 = fmaf(zb.z, wv.z, a0); a0 = fmaf(zb.w, wv.w, a0);
                }
                {
                    vf4 zb = zt[16 + f4];
                    a1 = fmaf(zb.x, wv.x, a1); a1 = fmaf(zb.y, wv.y, a1);
                    a1 = fmaf(zb.z, wv.z, a1); a1 = fmaf(zb.w, wv.w, a1);
                }
                {
                    vf4 zb = zt[32 + f4];
                    a2 = fmaf(zb.x, wv.x, a2); a2 = fmaf(zb.y, wv.y, a2);
                    a2 = fmaf(zb.z, wv.z, a2); a2 = fmaf(zb.w, wv.w, a2);
                }
                {
                    vf4 zb = zt[48 + f4];
                    a3 = fmaf(zb.x, wv.x, a3); a3 = fmaf(zb.y, wv.y, a3);
                    a3 = fmaf(zb.z, wv.z, a3); a3 = fmaf(zb.w, wv.w, a3);
                }
                {
                    vf4 zb = zt[64 + f4];
                    a4 = fmaf(zb.x, wv.x, a4); a4 = fmaf(zb.y, wv.y, a4);
                    a4 = fmaf(zb.z, wv.z, a4); a4 = fmaf(zb.w, wv.w, a4);
                }
                {
                    vf4 zb = zt[80 + f4];
                    a5 = fmaf(zb.x, wv.x, a5); a5 = fmaf(zb.y, wv.y, a5);
                    a5 = fmaf(zb.z, wv.z, a5); a5 = fmaf(zb.w, wv.w, a5);
                }
                {
                    vf4 zb = zt[96 + f4];
                    a6 = fmaf(zb.x, wv.x, a6); a6 = fmaf(zb.y, wv.y, a6);
                    a6 = fmaf(zb.z, wv.z, a6); a6 = fmaf(zb.w, wv.w, a6);
                }
                {
                    vf4 zb = zt[112 + f4];
                    a7 = fmaf(zb.x, wv.x, a7); a7 = fmaf(zb.y, wv.y, a7);
                    a7 = fmaf(zb.z, wv.z, a7); a7 = fmaf(zb.w, wv.w, a7);
                }
            }
            // distances + thread-local lex-min (order-agnostic lex compare)
            float d;
            d = fmaf(-2.0f, a0, sA[0]) + q;
            if (d < bd[0] || (d == bd[0] && c < bk[0])) { bd[0] = d; bk[0] = c; }
            d = fmaf(-2.0f, a1, sA[1]) + q;
            if (d < bd[1] || (d == bd[1] && c < bk[1])) { bd[1] = d; bk[1] = c; }
            d = fmaf(-2.0f, a2, sA[2]) + q;
            if (d < bd[2] || (d == bd[2] && c < bk[2])) { bd[2] = d; bk[2] = c; }
            d = fmaf(-2.0f, a3, sA[3]) + q;
            if (d < bd[3] || (d == bd[3] && c < bk[3])) { bd[3] = d; bk[3] = c; }
            d = fmaf(-2.0f, a4, sA[4]) + q;
            if (d < bd[4] || (d == bd[4] && c < bk[4])) { bd[4] = d; bk[4] = c; }
            d = fmaf(-2.0f, a5, sA[5]) + q;
            if (d < bd[5] || (d == bd[5] && c < bk[5])) { bd[5] = d; bk[5] = c; }
            d = fmaf(-2.0f, a6, sA[6]) + q;
            if (d < bd[6] || (d == bd[6] && c < bk[6])) { bd[6] = d; bk[6] = c; }
            d = fmaf(-2.0f, a7, sA[7]) + q;
            if (d < bd[7] || (d == bd[7] && c < bk[7])) { bd[7] = d; bk[7] = c; }
        }

        // ---- 64-lane butterfly lex-min; 8 independent row-chains interleave ----
#pragma unroll
        for (int off = 1; off < 64; off <<= 1) {
#pragma unroll
            for (int r = 0; r < RT; r++) {
                float od = __shfl_xor(bd[r], off, 64);
                int ok = __shfl_xor(bk[r], off, 64);
                if (od < bd[r] || (od == bd[r] && ok < bk[r])) { bd[r] = od; bk[r] = ok; }
            }
        }
        // all lanes now hold the final (bd,bk) for all 8 rows

        if (l == 0) {
#pragma unroll
            for (int r = 0; r < RT; r++) out_idx[row0 + r] = (float)bk[r];
        }

        // ---- zq & diff (z re-read from L1/L2, w gather from Wt; bit-exact) ----
#pragma unroll
        for (int h = 0; h < 2; h++) {
            const int rsel = l >> 4;              // 0..3 within half
            int kk = bk[4 * h + 0];
            if (rsel == 1) kk = bk[4 * h + 1];
            if (rsel == 2) kk = bk[4 * h + 2];
            if (rsel == 3) kk = bk[4 * h + 3];
            vf4 zvv = zt[(h << 6) + l];           // == z[row0 + 4h + rsel][chunk]
            vf4 wvv = ((const vf4*)Wt)[((size_t)kk << 4) + (l & 15)];
            vf4 zq, df;
            {
#pragma clang fp contract(off)
                vf4 d1 = wvv - zvv;
                zq = zvv + d1;
                df = d1 * d1;
            }
            ((vf4*)out_zq)[(size_t)row0 * 16 + (h << 6) + l] = zq;
            ((vf4*)out_diff)[(size_t)row0 * 16 + (h << 6) + l] = df;
        }

        // ---- one-hot: coalesced plain stores, 16 x 1KB per wave-tile ----
        {
            vf4* enc4 = (vf4*)enc + (size_t)row0 * 128;
#pragma unroll
            for (int jj = 0; jj < 16; jj++) {
                const int row = jj >> 1;     // compile-time per unrolled jj
                int kk = bk[row];
                int c = kk - ((l + ((jj & 1) << 6)) << 2);
                vf4 v;
                v.x = (c == 0) ? 1.0f : 0.0f;
                v.y = (c == 1) ? 1.0f : 0.0f;
                v.z = (c == 2) ? 1.0f : 0.0f;
                v.w = (c == 3) ? 1.0f : 0.0f;
                enc4[(jj << 6) + l] = v;
            }
        }
    }
}

extern "C" void kernel_launch(void* const* d_in, const int* in_sizes, int n_in,
                              void* d_out, int out_size, void* d_ws, size_t ws_size,
                              hipStream_t stream) {
    const float* z = (const float*)d_in[0];
    const float* W = (const float*)d_in[1];
    int N = in_sizes[0] / FDIM;  // 131072

    float* out = (float*)d_out;
    float* out_zq = out;
    float* out_idx = out_zq + (size_t)N * FDIM;
    float* enc = out_idx + N;
    float* out_diff = enc + (size_t)N * K_CLUSTERS;

    float* Wt = (float*)d_ws;
    float* wsq = Wt + K_CLUSTERS * FDIM;

    vq_prep<<<K_CLUSTERS, 64, 0, stream>>>(W, Wt, wsq);
    vq_fused<<<N / RPB, 1024, 0, stream>>>(z, W, Wt, wsq, out_zq, out_idx, enc, out_diff);
}

// Round 5
// 626.058 us; speedup vs baseline: 8.1349x; 8.1349x over previous
//
#include <hip/hip_runtime.h>

#define K_CLUSTERS 512
#define FDIM 64
#define RPB 512      // rows per block; grid = N/RPB = 256 (1 block/CU, LDS-bound)
#define RT 8         // rows per wave-tile
#define NTILES 4     // tiles per wave: RPB / (16 waves * RT)

typedef float vf4 __attribute__((ext_vector_type(4)));

// Transpose W [F=64][K=512] -> Wt [K][F] (for epilogue gather), wsq[k].
// UNCHANGED (absmax 0.0 proven).
__global__ __launch_bounds__(64) void vq_prep(const float* __restrict__ W,
                                              float* __restrict__ Wt,
                                              float* __restrict__ wsq) {
    int k = blockIdx.x;
    int f = threadIdx.x;
    float w = W[f * K_CLUSTERS + k];
    Wt[k * FDIM + f] = w;
    float s = w * w;
#pragma unroll
    for (int off = 32; off > 0; off >>= 1) s += __shfl_xor(s, off, 64);
    if (f == 0) wsq[k] = s;
}

// Fused argmin + zq + diff + one-hot.
// W in LDS (128 KB, XOR-swizzled incl. (c>>4)&3 quarter term). z broadcasts
// from global via a PROVABLY-UNIFORM base (readfirstlane) -> scalar s_load
// path, values in SGPRs, zero VGPR/VMEM cost.
// KEY FIX (rounds 2-4 post-mortem): at 1024-thread blocks the backend targets
// 8 waves/SIMD and caps VGPR at 64 no matter the working set -> ~11 GB scratch
// spill. amdgpu_waves_per_eu(4,4) pins the target to the 4 waves/SIMD that the
// 160KB-LDS single-block residency implies anyway -> VGPR cap 128, no spill.
// All arithmetic chains bit-identical to the proven kernels (absmax 0.0):
// ascending-f fmaf dot; fmaf(-2,dot,s)+wsq; 8-lane sumz chains + shfl_xor
// tree (== exact pairwise tree, proven round 3); contract-off epilogue;
// lex-min (d,k) == np.argmin first-index rule.
__global__ __launch_bounds__(1024)
__attribute__((amdgpu_waves_per_eu(4, 4)))
void vq_fused(const float* __restrict__ z,
              const float* __restrict__ W,
              const float* __restrict__ Wt,
              const float* __restrict__ wsq,
              float* __restrict__ out_zq,
              float* __restrict__ out_idx,
              float* __restrict__ enc,
              float* __restrict__ out_diff) {
    // sW4[c*16 + (f4 ^ (c&15) ^ ((c>>4)&3))] = W[4*f4..4*f4+3][c]
    __shared__ vf4 sW4[K_CLUSTERS * 16];   // 128 KB, the only LDS

    const int tid = threadIdx.x;
    // wave index as a compiler-provable SGPR (lane 0's tid >> 6): makes every
    // z-broadcast address uniform -> scalar-load path.
    const int w = __builtin_amdgcn_readfirstlane(tid) >> 6;
    const int l = tid & 63;
    const int xh = (l & 15) ^ ((l >> 4) & 3);   // read-side swizzle constant

    // ---- Stage W into LDS (coalesced vf4 reads, swizzled scalar writes) ----
    {
        float* sWf = (float*)sW4;
        const vf4* Wg4 = (const vf4*)W;
#pragma unroll
        for (int it = 0; it < 8; it++) {
            int u4 = it * 1024 + tid;       // vf4 index over W (8192 total)
            vf4 v = Wg4[u4];
            int u = u4 << 2;                // float index; 4 elems same f, c0..c0+3
            int f = u >> 9;
            int c0 = u & 511;
            int f4 = f >> 2, m = f & 3;
#pragma unroll
            for (int e = 0; e < 4; e++) {
                int c = c0 + e;
                int chunk = f4 ^ (c & 15) ^ ((c >> 4) & 3);
                sWf[c * 64 + (chunk << 2) + m] = v[e];
            }
        }
    }
    __syncthreads();  // the only barrier in the kernel

    const int rowW = blockIdx.x * RPB + w * (RT * NTILES);
    const vf4* zg4 = (const vf4*)z;

#pragma unroll 1
    for (int t = 0; t < NTILES; t++) {
        const int row0 = rowW + t * RT;     // wave-uniform (SGPR)

        // ---- sumz: 8 lanes per row, one exact accumulator chain per lane ----
        // (proven bit-exact in round 3)
        float srow;
        {
            const float* zr = z + (size_t)(row0 + (l >> 3)) * FDIM;
            const int j = l & 7;
            float rj;
            {
#pragma clang fp contract(off)
                rj = zr[j] * zr[j];
#pragma unroll
                for (int b = 8; b < 64; b += 8) rj += zr[b + j] * zr[b + j];
            }
            float s01 = rj + __shfl_xor(rj, 1, 64);
            float s03 = s01 + __shfl_xor(s01, 2, 64);
            srow = s03 + __shfl_xor(s03, 4, 64);
        }
        float sA[RT];
#pragma unroll
        for (int r = 0; r < RT; r++) sA[r] = __shfl(srow, r << 3, 64);

        float bd[RT];
        int bk[RT];
#pragma unroll
        for (int r = 0; r < RT; r++) { bd[r] = INFINITY; bk[r] = 0; }

        const vf4* zt = zg4 + (size_t)row0 * 16;  // uniform z tile base (SGPR)

        // ---- 8 passes: lane l owns cluster c = pass*64 + l ----
#pragma unroll 1
        for (int pass = 0; pass < 8; pass++) {
            const int c = (pass << 6) + l;
            const float q = wsq[c];
            const vf4* wB = sW4 + ((size_t)c << 4);
            float a0 = 0.0f, a1 = 0.0f, a2 = 0.0f, a3 = 0.0f;
            float a4 = 0.0f, a5 = 0.0f, a6 = 0.0f, a7 = 0.0f;
#pragma unroll 4
            for (int f4 = 0; f4 < 16; f4++) {
                const int sl = f4 ^ xh;        // swizzled chunk for this lane
                vf4 wv = wB[sl];
                {
                    vf4 zb = zt[f4];           // uniform -> s_load broadcast
                    a0 = fmaf(zb.x, wv.x, a0); a0 = fmaf(zb.y, wv.y, a0);
                    a0 = fmaf(zb.z, wv.z, a0); a0 = fmaf(zb.w, wv.w, a0);
                }
                {
                    vf4 zb = zt[16 + f4];
                    a1 = fmaf(zb.x, wv.x, a1); a1 = fmaf(zb.y, wv.y, a1);
                    a1 = fmaf(zb.z, wv.z, a1); a1 = fmaf(zb.w, wv.w, a1);
                }
                {
                    vf4 zb = zt[32 + f4];
                    a2 = fmaf(zb.x, wv.x, a2); a2 = fmaf(zb.y, wv.y, a2);
                    a2 = fmaf(zb.z, wv.z, a2); a2 = fmaf(zb.w, wv.w, a2);
                }
                {
                    vf4 zb = zt[48 + f4];
                    a3 = fmaf(zb.x, wv.x, a3); a3 = fmaf(zb.y, wv.y, a3);
                    a3 = fmaf(zb.z, wv.z, a3); a3 = fmaf(zb.w, wv.w, a3);
                }
                {
                    vf4 zb = zt[64 + f4];
                    a4 = fmaf(zb.x, wv.x, a4); a4 = fmaf(zb.y, wv.y, a4);
                    a4 = fmaf(zb.z, wv.z, a4); a4 = fmaf(zb.w, wv.w, a4);
                }
                {
                    vf4 zb = zt[80 + f4];
                    a5 = fmaf(zb.x, wv.x, a5); a5 = fmaf(zb.y, wv.y, a5);
                    a5 = fmaf(zb.z, wv.z, a5); a5 = fmaf(zb.w, wv.w, a5);
                }
                {
                    vf4 zb = zt[96 + f4];
                    a6 = fmaf(zb.x, wv.x, a6); a6 = fmaf(zb.y, wv.y, a6);
                    a6 = fmaf(zb.z, wv.z, a6); a6 = fmaf(zb.w, wv.w, a6);
                }
                {
                    vf4 zb = zt[112 + f4];
                    a7 = fmaf(zb.x, wv.x, a7); a7 = fmaf(zb.y, wv.y, a7);
                    a7 = fmaf(zb.z, wv.z, a7); a7 = fmaf(zb.w, wv.w, a7);
                }
            }
            // distances + thread-local lex-min (order-agnostic lex compare)
            float d;
            d = fmaf(-2.0f, a0, sA[0]) + q;
            if (d < bd[0] || (d == bd[0] && c < bk[0])) { bd[0] = d; bk[0] = c; }
            d = fmaf(-2.0f, a1, sA[1]) + q;
            if (d < bd[1] || (d == bd[1] && c < bk[1])) { bd[1] = d; bk[1] = c; }
            d = fmaf(-2.0f, a2, sA[2]) + q;
            if (d < bd[2] || (d == bd[2] && c < bk[2])) { bd[2] = d; bk[2] = c; }
            d = fmaf(-2.0f, a3, sA[3]) + q;
            if (d < bd[3] || (d == bd[3] && c < bk[3])) { bd[3] = d; bk[3] = c; }
            d = fmaf(-2.0f, a4, sA[4]) + q;
            if (d < bd[4] || (d == bd[4] && c < bk[4])) { bd[4] = d; bk[4] = c; }
            d = fmaf(-2.0f, a5, sA[5]) + q;
            if (d < bd[5] || (d == bd[5] && c < bk[5])) { bd[5] = d; bk[5] = c; }
            d = fmaf(-2.0f, a6, sA[6]) + q;
            if (d < bd[6] || (d == bd[6] && c < bk[6])) { bd[6] = d; bk[6] = c; }
            d = fmaf(-2.0f, a7, sA[7]) + q;
            if (d < bd[7] || (d == bd[7] && c < bk[7])) { bd[7] = d; bk[7] = c; }
        }

        // ---- 64-lane butterfly lex-min; 8 independent row-chains interleave ----
#pragma unroll
        for (int off = 1; off < 64; off <<= 1) {
#pragma unroll
            for (int r = 0; r < RT; r++) {
                float od = __shfl_xor(bd[r], off, 64);
                int ok = __shfl_xor(bk[r], off, 64);
                if (od < bd[r] || (od == bd[r] && ok < bk[r])) { bd[r] = od; bk[r] = ok; }
            }
        }
        // all lanes now hold the final (bd,bk) for all 8 rows

        if (l == 0) {
#pragma unroll
            for (int r = 0; r < RT; r++) out_idx[row0 + r] = (float)bk[r];
        }

        // ---- zq & diff (z re-read from L1/L2, w gather from Wt; bit-exact) ----
#pragma unroll
        for (int h = 0; h < 2; h++) {
            const int rsel = l >> 4;              // 0..3 within half
            int kk = bk[4 * h + 0];
            if (rsel == 1) kk = bk[4 * h + 1];
            if (rsel == 2) kk = bk[4 * h + 2];
            if (rsel == 3) kk = bk[4 * h + 3];
            vf4 zvv = zt[(h << 6) + l];           // == z[row0 + 4h + rsel][chunk]
            vf4 wvv = ((const vf4*)Wt)[((size_t)kk << 4) + (l & 15)];
            vf4 zq, df;
            {
#pragma clang fp contract(off)
                vf4 d1 = wvv - zvv;
                zq = zvv + d1;
                df = d1 * d1;
            }
            ((vf4*)out_zq)[(size_t)row0 * 16 + (h << 6) + l] = zq;
            ((vf4*)out_diff)[(size_t)row0 * 16 + (h << 6) + l] = df;
        }

        // ---- one-hot: coalesced plain stores, 16 x 1KB per wave-tile ----
        {
            vf4* enc4 = (vf4*)enc + (size_t)row0 * 128;
#pragma unroll
            for (int jj = 0; jj < 16; jj++) {
                const int row = jj >> 1;     // compile-time per unrolled jj
                int kk = bk[row];
                int c = kk - ((l + ((jj & 1) << 6)) << 2);
                vf4 v;
                v.x = (c == 0) ? 1.0f : 0.0f;
                v.y = (c == 1) ? 1.0f : 0.0f;
                v.z = (c == 2) ? 1.0f : 0.0f;
                v.w = (c == 3) ? 1.0f : 0.0f;
                enc4[(jj << 6) + l] = v;
            }
        }
    }
}

extern "C" void kernel_launch(void* const* d_in, const int* in_sizes, int n_in,
                              void* d_out, int out_size, void* d_ws, size_t ws_size,
                              hipStream_t stream) {
    const float* z = (const float*)d_in[0];
    const float* W = (const float*)d_in[1];
    int N = in_sizes[0] / FDIM;  // 131072

    float* out = (float*)d_out;
    float* out_zq = out;
    float* out_idx = out_zq + (size_t)N * FDIM;
    float* enc = out_idx + N;
    float* out_diff = enc + (size_t)N * K_CLUSTERS;

    float* Wt = (float*)d_ws;
    float* wsq = Wt + K_CLUSTERS * FDIM;

    vq_prep<<<K_CLUSTERS, 64, 0, stream>>>(W, Wt, wsq);
    vq_fused<<<N / RPB, 1024, 0, stream>>>(z, W, Wt, wsq, out_zq, out_idx, enc, out_diff);
}

// Round 6
// 447.389 us; speedup vs baseline: 11.3836x; 1.3994x over previous
//
#include <hip/hip_runtime.h>

#define K_CLUSTERS 512
#define FDIM 64
#define RPB 512      // rows per block; grid = N/RPB = 256 (1 block/CU, LDS-bound)
#define RT 8         // rows per wave-tile
#define NTILES 4     // tiles per wave: RPB / (16 waves * RT)
#define WSTRIDE 17   // vf4 per LDS W row (16 + 1 pad -> bank-quad = (c+f4)%8)

typedef float vf4 __attribute__((ext_vector_type(4)));

// Transpose W [F=64][K=512] -> Wt [K][F] (for epilogue gather), wsq[k].
// UNCHANGED (absmax 0.0 proven).
__global__ __launch_bounds__(64) void vq_prep(const float* __restrict__ W,
                                              float* __restrict__ Wt,
                                              float* __restrict__ wsq) {
    int k = blockIdx.x;
    int f = threadIdx.x;
    float w = W[f * K_CLUSTERS + k];
    Wt[k * FDIM + f] = w;
    float s = w * w;
#pragma unroll
    for (int off = 32; off > 0; off >>= 1) s += __shfl_xor(s, off, 64);
    if (f == 0) wsq[k] = s;
}

// Fused argmin + zq + diff + one-hot.
// Round-6 structure: CPL=4 (round 3's hot loop, viable now that
// amdgpu_waves_per_eu(4,4) raises the VGPR cap to 128 -- round 3 died only to
// the 64-reg cap) -> z-broadcast VMEM instrs drop 4x (the round-5 limiter:
// uniform global_load still streams 1KB/instr through the L1 return bus, ~218
// us of VMEM pipe at CPL=1). LDS W rows padded to 17 vf4 (272B): row stride
// mod 32 banks = 4, so lanes (c=base+l) spread evenly over all 8 bank-quads --
// replaces the XOR swizzle that left row starts bank-0-aligned (6.8M
// conflicts).
// All arithmetic chains bit-identical to the proven kernels (absmax 0.0):
// ascending-f fmaf dot; fmaf(-2,dot,s)+wsq; 8-lane sumz chains + shfl_xor
// tree (proven round 3/5); contract-off epilogue; lex-min (d,k) == np.argmin
// first-index rule (jj ascending within lane, proven round 3).
__global__ __launch_bounds__(1024)
__attribute__((amdgpu_waves_per_eu(4, 4)))
void vq_fused(const float* __restrict__ z,
              const float* __restrict__ W,
              const float* __restrict__ Wt,
              const float* __restrict__ wsq,
              float* __restrict__ out_zq,
              float* __restrict__ out_idx,
              float* __restrict__ enc,
              float* __restrict__ out_diff) {
    __shared__ vf4 sW4[K_CLUSTERS * WSTRIDE];   // 136 KB, the only LDS

    const int tid = threadIdx.x;
    // wave index as a compiler-provable SGPR: z-tile base stays uniform.
    const int w = __builtin_amdgcn_readfirstlane(tid) >> 6;
    const int l = tid & 63;

    // ---- Stage W into LDS (coalesced vf4 reads, strided scalar writes; the
    // write-side bank conflicts are a one-time ~5 us cost) ----
    {
        float* sWf = (float*)sW4;
        const vf4* Wg4 = (const vf4*)W;
#pragma unroll
        for (int it = 0; it < 8; it++) {
            int u4 = it * 1024 + tid;       // vf4 index over W (8192 total)
            vf4 v = Wg4[u4];
            int u = u4 << 2;                // float index; 4 elems same f, c0..c0+3
            int f = u >> 9;
            int c0 = u & 511;
            int f4 = f >> 2, m = f & 3;
#pragma unroll
            for (int e = 0; e < 4; e++) {
                int c = c0 + e;
                sWf[c * (4 * WSTRIDE) + (f4 << 2) + m] = v[e];
            }
        }
    }
    __syncthreads();  // the only barrier in the kernel

    const int rowW = blockIdx.x * RPB + w * (RT * NTILES);
    const vf4* zg4 = (const vf4*)z;

#pragma unroll 1
    for (int t = 0; t < NTILES; t++) {
        const int row0 = rowW + t * RT;     // wave-uniform (SGPR)

        // ---- sumz: 8 lanes per row, one exact accumulator chain per lane ----
        // (proven bit-exact rounds 3/5)
        float srow;
        {
            const float* zr = z + (size_t)(row0 + (l >> 3)) * FDIM;
            const int j = l & 7;
            float rj;
            {
#pragma clang fp contract(off)
                rj = zr[j] * zr[j];
#pragma unroll
                for (int b = 8; b < 64; b += 8) rj += zr[b + j] * zr[b + j];
            }
            float s01 = rj + __shfl_xor(rj, 1, 64);
            float s03 = s01 + __shfl_xor(s01, 2, 64);
            srow = s03 + __shfl_xor(s03, 4, 64);
        }
        float sA[RT];
#pragma unroll
        for (int r = 0; r < RT; r++) sA[r] = __shfl(srow, r << 3, 64);

        float bd[RT];
        int bk[RT];
#pragma unroll
        for (int r = 0; r < RT; r++) { bd[r] = INFINITY; bk[r] = 0; }

        const vf4* zt = zg4 + (size_t)row0 * 16;  // uniform z tile base (SGPR)

        // ---- two passes: lane l owns c = pass*256 + jj*64 + l, jj=0..3 ----
#pragma unroll 1
        for (int pass = 0; pass < 2; pass++) {
            const int cBase = (pass << 8) + l;
            float q0 = wsq[cBase];
            float q1 = wsq[cBase + 64];
            float q2 = wsq[cBase + 128];
            float q3 = wsq[cBase + 192];
            float acc[RT][4];
#pragma unroll
            for (int r = 0; r < RT; r++)
#pragma unroll
                for (int jj = 0; jj < 4; jj++) acc[r][jj] = 0.0f;
            const vf4* wB = sW4 + cBase * WSTRIDE;
#pragma unroll 2
            for (int f4 = 0; f4 < 16; f4++) {
                vf4 wv0 = wB[f4];                       // jj stride = 64*WSTRIDE vf4
                vf4 wv1 = wB[64 * WSTRIDE + f4];
                vf4 wv2 = wB[128 * WSTRIDE + f4];
                vf4 wv3 = wB[192 * WSTRIDE + f4];
#pragma unroll
                for (int r = 0; r < RT; r++) {
                    vf4 zb = zt[(r << 4) + f4];         // uniform 16B broadcast
                    float a0 = acc[r][0], a1 = acc[r][1], a2 = acc[r][2], a3 = acc[r][3];
                    a0 = fmaf(zb.x, wv0.x, a0); a1 = fmaf(zb.x, wv1.x, a1);
                    a2 = fmaf(zb.x, wv2.x, a2); a3 = fmaf(zb.x, wv3.x, a3);
                    a0 = fmaf(zb.y, wv0.y, a0); a1 = fmaf(zb.y, wv1.y, a1);
                    a2 = fmaf(zb.y, wv2.y, a2); a3 = fmaf(zb.y, wv3.y, a3);
                    a0 = fmaf(zb.z, wv0.z, a0); a1 = fmaf(zb.z, wv1.z, a1);
                    a2 = fmaf(zb.z, wv2.z, a2); a3 = fmaf(zb.z, wv3.z, a3);
                    a0 = fmaf(zb.w, wv0.w, a0); a1 = fmaf(zb.w, wv1.w, a1);
                    a2 = fmaf(zb.w, wv2.w, a2); a3 = fmaf(zb.w, wv3.w, a3);
                    acc[r][0] = a0; acc[r][1] = a1; acc[r][2] = a2; acc[r][3] = a3;
                }
            }
            // distances + thread-local lex-min (jj ascending == c ascending)
#pragma unroll
            for (int r = 0; r < RT; r++) {
                float d0 = fmaf(-2.0f, acc[r][0], sA[r]) + q0;
                float d1 = fmaf(-2.0f, acc[r][1], sA[r]) + q1;
                float d2 = fmaf(-2.0f, acc[r][2], sA[r]) + q2;
                float d3 = fmaf(-2.0f, acc[r][3], sA[r]) + q3;
                if (d0 < bd[r] || (d0 == bd[r] && cBase < bk[r])) { bd[r] = d0; bk[r] = cBase; }
                if (d1 < bd[r] || (d1 == bd[r] && cBase + 64 < bk[r])) { bd[r] = d1; bk[r] = cBase + 64; }
                if (d2 < bd[r] || (d2 == bd[r] && cBase + 128 < bk[r])) { bd[r] = d2; bk[r] = cBase + 128; }
                if (d3 < bd[r] || (d3 == bd[r] && cBase + 192 < bk[r])) { bd[r] = d3; bk[r] = cBase + 192; }
            }
        }

        // ---- 64-lane butterfly lex-min; 8 independent row-chains interleave ----
#pragma unroll
        for (int off = 1; off < 64; off <<= 1) {
#pragma unroll
            for (int r = 0; r < RT; r++) {
                float od = __shfl_xor(bd[r], off, 64);
                int ok = __shfl_xor(bk[r], off, 64);
                if (od < bd[r] || (od == bd[r] && ok < bk[r])) { bd[r] = od; bk[r] = ok; }
            }
        }
        // all lanes now hold the final (bd,bk) for all 8 rows

        if (l == 0) {
#pragma unroll
            for (int r = 0; r < RT; r++) out_idx[row0 + r] = (float)bk[r];
        }

        // ---- zq & diff (z re-read from L1/L2, w gather from Wt; bit-exact) ----
#pragma unroll
        for (int h = 0; h < 2; h++) {
            const int rsel = l >> 4;              // 0..3 within half
            int kk = bk[4 * h + 0];
            if (rsel == 1) kk = bk[4 * h + 1];
            if (rsel == 2) kk = bk[4 * h + 2];
            if (rsel == 3) kk = bk[4 * h + 3];
            vf4 zvv = zt[(h << 6) + l];           // == z[row0 + 4h + rsel][chunk]
            vf4 wvv = ((const vf4*)Wt)[((size_t)kk << 4) + (l & 15)];
            vf4 zq, df;
            {
#pragma clang fp contract(off)
                vf4 d1 = wvv - zvv;
                zq = zvv + d1;
                df = d1 * d1;
            }
            ((vf4*)out_zq)[(size_t)row0 * 16 + (h << 6) + l] = zq;
            ((vf4*)out_diff)[(size_t)row0 * 16 + (h << 6) + l] = df;
        }

        // ---- one-hot: coalesced plain stores, 16 x 1KB per wave-tile ----
        {
            vf4* enc4 = (vf4*)enc + (size_t)row0 * 128;
#pragma unroll
            for (int jj = 0; jj < 16; jj++) {
                const int row = jj >> 1;     // compile-time per unrolled jj
                int kk = bk[row];
                int c = kk - ((l + ((jj & 1) << 6)) << 2);
                vf4 v;
                v.x = (c == 0) ? 1.0f : 0.0f;
                v.y = (c == 1) ? 1.0f : 0.0f;
                v.z = (c == 2) ? 1.0f : 0.0f;
                v.w = (c == 3) ? 1.0f : 0.0f;
                enc4[(jj << 6) + l] = v;
            }
        }
    }
}

extern "C" void kernel_launch(void* const* d_in, const int* in_sizes, int n_in,
                              void* d_out, int out_size, void* d_ws, size_t ws_size,
                              hipStream_t stream) {
    const float* z = (const float*)d_in[0];
    const float* W = (const float*)d_in[1];
    int N = in_sizes[0] / FDIM;  // 131072

    float* out = (float*)d_out;
    float* out_zq = out;
    float* out_idx = out_zq + (size_t)N * FDIM;
    float* enc = out_idx + N;
    float* out_diff = enc + (size_t)N * K_CLUSTERS;

    float* Wt = (float*)d_ws;
    float* wsq = Wt + K_CLUSTERS * FDIM;

    vq_prep<<<K_CLUSTERS, 64, 0, stream>>>(W, Wt, wsq);
    vq_fused<<<N / RPB, 1024, 0, stream>>>(z, W, Wt, wsq, out_zq, out_idx, enc, out_diff);
}